// Round 5
// baseline (296.416 us; speedup 1.0000x reference)
//
#include <hip/hip_runtime.h>
#include <hip/hip_bf16.h>
#include <math.h>

// Problem constants
#define NB    16
#define NSEQ  2048
#define MROWS (NB*NSEQ)        // 32768
#define NPAD  2176             // gemm1 cols: q [0,1056) + k [1056,2112) + pad
// Within q/k: freq F = h*65+f (0..519, pad 528). gg=F>>4, t=F&15:
//   re at col region*1056 + gg*32 + t, im at +16  -> re/im same lane, 16 apart.
// XQKT: [row F' = region*528 + F][m], 1088 rows.
#define QKT_ROWS 1088
#define NCH   16               // attm e-chunks of 128

typedef __attribute__((ext_vector_type(8))) short bf16x8;
typedef __attribute__((ext_vector_type(4))) float f32x4;

__device__ __forceinline__ void g2l16(const void* g, void* l) {
    __builtin_amdgcn_global_load_lds(
        (const __attribute__((address_space(1))) void*)g,
        (__attribute__((address_space(3))) void*)l, 16, 0, 0);
}

__device__ __forceinline__ ushort f2bfu(float x) {
    __hip_bfloat16 t = __float2bfloat16(x);
    return *reinterpret_cast<ushort*>(&t);
}

// ---------------------------------------------------------------------------
// Fused small preps: [0,4096) x->Xb cast; [4096,4224) Wv bf16 cast;
// [4224,4744) Gcat (irfft basis @ w_out); [4744,4760) Fcs table.
// ---------------------------------------------------------------------------
__global__ __launch_bounds__(256) void k_misc(const float* __restrict__ x,
                                              const float* __restrict__ wqkv,
                                              const float* __restrict__ wout,
                                              __hip_bfloat16* __restrict__ Xb,
                                              ushort* __restrict__ Wvb,
                                              ushort* __restrict__ Gcat,
                                              ushort* __restrict__ Fcs) {
    __shared__ float tc[128], ts[128];
    int tid = threadIdx.x;
    int bid = blockIdx.x;
    if (bid < 4096) {
        int i = bid * 256 + tid;
        float4 v = ((const float4*)x)[i];
        __hip_bfloat16 o[4] = {__float2bfloat16(v.x), __float2bfloat16(v.y),
                               __float2bfloat16(v.z), __float2bfloat16(v.w)};
        *(ushort4*)((ushort*)Xb + (size_t)i * 4) = *(const ushort4*)o;
    } else if (bid < 4224) {
        int u = bid - 4096;                // 0..127
        float4 v = *(const float4*)(wqkv + (size_t)u * 3072 + 2048 + tid * 4);
        ushort o[4] = {f2bfu(v.x), f2bfu(v.y), f2bfu(v.z), f2bfu(v.w)};
        *(ushort4*)(Wvb + (size_t)u * 1024 + tid * 4) = *(const ushort4*)o;
    } else if (bid < 4744) {
        int hx = bid - 4224;               // 0..519
        if (tid < 128) {
            float a = (float)tid / 64.0f;
            tc[tid] = cospif(a);
            ts[tid] = sinpif(a);
        }
        __syncthreads();
        if (tid < 128) {
            int h = hx / 65, xx = hx - h * 65;
            float w = (xx == 0 || xx == 64) ? (1.0f / 128.0f) : (2.0f / 128.0f);
            float ar = 0.f, ai = 0.f;
            #pragma unroll 8
            for (int d = 0; d < 128; ++d) {
                float wv = wout[(size_t)(h * 128 + d) * 128 + tid];
                int m = (xx * d) & 127;
                ar = fmaf(wv, tc[m], ar);
                ai = fmaf(wv, ts[m], ai);
            }
            ushort* gp = Gcat + ((size_t)(h * 128 + tid)) * 160;
            gp[xx] = f2bfu(ar * w);
            gp[80 + xx] = f2bfu(-ai * w);
            if (xx == 0) {
                for (int k = 65; k < 80; ++k) gp[k] = 0;
                for (int k = 145; k < 160; ++k) gp[k] = 0;
            }
        }
    } else {
        // Fcs[r][y]: r<128 cos(2pi r y/128); r>=128 -sin(...); y>=65 -> 0
        int r = (bid - 4744) * 16 + (tid >> 4);
        int d = r & 127;
        int y0 = (tid & 15) * 6;
        #pragma unroll
        for (int k = 0; k < 6; ++k) {
            int y = y0 + k;
            float v = 0.f;
            if (y < 65) {
                float a = (float)((d * y) & 127) / 64.0f;
                v = (r < 128) ? cospif(a) : -sinpif(a);
            }
            Fcs[r * 96 + y] = f2bfu(v);
        }
    }
}

// ---------------------------------------------------------------------------
// q/k DFT fold into Wt. Grid (32, 2): (reg,h,c-half) x r-half.
// n = reg*1056 + ((F>>4)<<5) + (F&15) + ri*16, F=h*65+f.
// ---------------------------------------------------------------------------
__global__ __launch_bounds__(256) void k_prep_wqk(const float* __restrict__ wqkv,
                                                  __hip_bfloat16* __restrict__ Wt) {
    __shared__ float lw[64][129];
    __shared__ float tc[128], ts[128];
    int tid = threadIdx.x;
    int bid = blockIdx.x;
    int ry = blockIdx.y;
    int reg = bid >> 4;
    int h = (bid >> 1) & 7;
    int c0 = (bid & 1) * 64;
    if (tid < 128) {
        float a = (float)tid / 64.0f;
        tc[tid] = cospif(a);
        ts[tid] = sinpif(a);
    }
    #pragma unroll
    for (int it = 0; it < 8; ++it) {
        int idx = it * 256 + tid;
        int cl = idx >> 5;
        int d4 = (idx & 31) << 2;
        float4 v = *(const float4*)(wqkv + (size_t)(c0 + cl) * 3072 + reg * 1024 + h * 128 + d4);
        lw[cl][d4] = v.x; lw[cl][d4 + 1] = v.y; lw[cl][d4 + 2] = v.z; lw[cl][d4 + 3] = v.w;
    }
    __syncthreads();
    int cl = tid & 63;
    int rr = tid >> 6;
    int rend = ry ? 130 : 65;
    for (int r = ry * 65 + rr; r < rend; r += 4) {
        int f = r >> 1, ri = r & 1;
        float acc = 0.f;
        if (ri) {
            #pragma unroll 16
            for (int d = 0; d < 128; ++d) acc = fmaf(lw[cl][d], -ts[(f * d) & 127], acc);
        } else {
            #pragma unroll 16
            for (int d = 0; d < 128; ++d) acc = fmaf(lw[cl][d], tc[(f * d) & 127], acc);
        }
        int F = h * 65 + f;
        int n = reg * 1056 + ((F >> 4) << 5) + (F & 15) + ri * 16;
        Wt[(size_t)n * 128 + c0 + cl] = __float2bfloat16(acc * (1.0f / 65.0f));
    }
}

// ---------------------------------------------------------------------------
// GEMM1 (MFMA): Xb[32768,128] @ Wt^T (q/k only). 128x128 tile, K=128 one shot.
// Epilogue: (re,im) same lane, adjacent j-tiles -> magnitude -> XQKT packed.
// ---------------------------------------------------------------------------
__global__ __launch_bounds__(256) void k_gemm1m(const __hip_bfloat16* __restrict__ Xb,
                                                const __hip_bfloat16* __restrict__ Wt,
                                                ushort* __restrict__ XQKT) {
    __shared__ ushort As[128 * 128];
    __shared__ ushort Bs[128 * 128];
    int tid = threadIdx.x;
    int wave = tid >> 6, lane = tid & 63;
    int n0 = blockIdx.x * 128;
    int m0 = blockIdx.y * 128;
    const ushort* ga = (const ushort*)Xb + (size_t)m0 * 128;
    const ushort* gb = (const ushort*)Wt + (size_t)n0 * 128;
    #pragma unroll
    for (int it = 0; it < 8; ++it) {
        int q = wave * 512 + it * 64 + lane;
        int row = q >> 4, cp = q & 15;
        int gc = cp ^ (row & 15);
        int lbase = (wave * 512 + it * 64) * 8;
        g2l16(ga + (size_t)row * 128 + gc * 8, As + lbase);
        g2l16(gb + (size_t)row * 128 + gc * 8, Bs + lbase);
    }
    __syncthreads();

    f32x4 acc[4][4];
    #pragma unroll
    for (int i = 0; i < 4; ++i)
        #pragma unroll
        for (int j = 0; j < 4; ++j) acc[i][j] = (f32x4){0.f, 0.f, 0.f, 0.f};

    int lr = lane & 15, lk = lane >> 4;
    int wr = (wave >> 1) * 64, wc = (wave & 1) * 64;
    #pragma unroll
    for (int kk = 0; kk < 4; ++kk) {
        bf16x8 af[4], bfr[4];
        int c = kk * 4 + lk;
        #pragma unroll
        for (int i = 0; i < 4; ++i) {
            int m = wr + i * 16 + lr;
            af[i] = *(const bf16x8*)(As + m * 128 + (c ^ (m & 15)) * 8);
            int n = wc + i * 16 + lr;
            bfr[i] = *(const bf16x8*)(Bs + n * 128 + (c ^ (n & 15)) * 8);
        }
        #pragma unroll
        for (int i = 0; i < 4; ++i)
            #pragma unroll
            for (int j = 0; j < 4; ++j)
                acc[i][j] = __builtin_amdgcn_mfma_f32_16x16x32_bf16(af[i], bfr[j], acc[i][j], 0, 0, 0);
    }

    #pragma unroll
    for (int i = 0; i < 4; ++i) {
        int gr = m0 + wr + i * 16 + lk * 4;
        #pragma unroll
        for (int jp = 0; jp < 2; ++jp) {
            int cb = n0 + wc + jp * 32;
            if (cb < 2112) {
                int region = (cb >= 1056) ? 1 : 0;
                int local = cb - region * 1056;
                int row = region * 528 + ((local >> 5) << 4) + lr;
                f32x4 re = acc[i][2 * jp], im = acc[i][2 * jp + 1];
                union { ushort4 u4; ushort u[4]; } pk;
                #pragma unroll
                for (int r = 0; r < 4; ++r)
                    pk.u[r] = f2bfu(sqrtf(re[r] * re[r] + im[r] * im[r]));
                *(ushort4*)(XQKT + (size_t)row * MROWS + gr) = pk.u4;
            }
        }
    }
}

// ---------------------------------------------------------------------------
// att partials via MFMA. One wave per (bh, 128-e chunk). 5x5 tiles of 16x16,
// 4 K-substeps of 32 e. LDS pitch 5 chunks -> conflict-free.
// ---------------------------------------------------------------------------
__global__ __launch_bounds__(64) void k_attm(const ushort* __restrict__ XQKT,
                                             float* __restrict__ attp) {
    __shared__ ushort S[800 * 8];          // Q: chunks 0..399, K: 400..799
    int lane = threadIdx.x;
    int bh = blockIdx.x, ch = blockIdx.y;
    int b = bh >> 3, h = bh & 7;
    size_t e0 = (size_t)b * NSEQ + ch * 128;
    int qrow0 = h * 65, krow0 = 528 + h * 65;

    int srow[13], sco[13];
    #pragma unroll
    for (int r = 0; r < 13; ++r) {
        int s = r * 64 + lane;
        int mat = (s >= 400) ? 1 : 0;
        int ci = s - mat * 400;
        int f = ci / 5;
        int cp = ci - f * 5;
        srow[r] = (mat ? krow0 : qrow0) + f;
        sco[r] = (cp < 4) ? cp * 8 : 0;
    }

    f32x4 acc[5][5];
    #pragma unroll
    for (int i = 0; i < 5; ++i)
        #pragma unroll
        for (int j = 0; j < 5; ++j) acc[i][j] = (f32x4){0.f, 0.f, 0.f, 0.f};
    int lr = lane & 15, quad = lane >> 4;

    for (int sub = 0; sub < 4; ++sub) {
        __syncthreads();
        size_t ebase = e0 + sub * 32;
        #pragma unroll
        for (int r = 0; r < 12; ++r)
            g2l16(XQKT + (size_t)srow[r] * MROWS + ebase + sco[r], S + r * 64 * 8);
        if (lane < 32)
            g2l16(XQKT + (size_t)srow[12] * MROWS + ebase + sco[12], S + 12 * 64 * 8);
        __syncthreads();
        bf16x8 af[5], bfr[5];
        #pragma unroll
        for (int t5 = 0; t5 < 5; ++t5) {
            af[t5]  = *(const bf16x8*)(S + (t5 * 16 + lr) * 40 + quad * 8);
            bfr[t5] = *(const bf16x8*)(S + 3200 + (t5 * 16 + lr) * 40 + quad * 8);
        }
        #pragma unroll
        for (int tr = 0; tr < 5; ++tr)
            #pragma unroll
            for (int tc = 0; tc < 5; ++tc)
                acc[tr][tc] = __builtin_amdgcn_mfma_f32_16x16x32_bf16(af[tr], bfr[tc], acc[tr][tc], 0, 0, 0);
    }

    float* outp = attp + ((size_t)bh * NCH + ch) * 4225;
    #pragma unroll
    for (int tr = 0; tr < 5; ++tr) {
        #pragma unroll
        for (int tc = 0; tc < 5; ++tc) {
            int y = tc * 16 + lr;
            int x0 = tr * 16 + quad * 4;
            if (y < 65) {
                #pragma unroll
                for (int rr = 0; rr < 4; ++rr) {
                    int x = x0 + rr;
                    if (x < 65) outp[x * 65 + y] = acc[tr][tc][rr];
                }
            }
        }
    }
}

// ---------------------------------------------------------------------------
// Fused softmax + T + P per (chalf, bh) block:
// softmax: sum NCH partials, softmax over y -> Batt (LDS, bf16, B-layout)
// Stage 1: [Fc;Fs][256,96] @ Batt^T -> A3 via LDS (C->A layout, pads zeroed)
// Stage 2: A3[128,160] @ Gcat^T -> Pt[b][c][h*128+d]
// Pitches 104/168 -> conflict-free fragment reads.
// ---------------------------------------------------------------------------
__global__ __launch_bounds__(256) void k_TP(const float* __restrict__ attp,
                                            const ushort* __restrict__ Fcs,
                                            const ushort* __restrict__ Gcat,
                                            ushort* __restrict__ Pt) {
    __shared__ ushort Batt[80 * 104];
    __shared__ ushort A3[128 * 168];
    int tid = threadIdx.x;
    int wave = tid >> 6, lane = tid & 63;
    int lr = lane & 15, quad = lane >> 4;
    int chalf = blockIdx.x, bh = blockIdx.y;
    int b = bh >> 3, h = bh & 7;

    uint2 z2; z2.x = 0; z2.y = 0;
    uint2* A3v = (uint2*)A3;
    #pragma unroll 4
    for (int i = tid; i < 128 * 168 / 4; i += 256) A3v[i] = z2;
    uint2* Bv = (uint2*)Batt;
    #pragma unroll 4
    for (int i = tid; i < 80 * 104 / 4; i += 256) Bv[i] = z2;
    __syncthreads();

    // fused softmax: one wave per x-row
    const float* ap = attp + (size_t)bh * NCH * 4225;
    for (int xr = wave; xr < 65; xr += 4) {
        float v0 = 0.f, v1 = 0.f;
        #pragma unroll
        for (int c = 0; c < NCH; ++c) {
            const float* row = ap + (size_t)c * 4225 + xr * 65;
            v0 += row[lane];
            if (lane == 0) v1 += row[64];
        }
        float v1b = __shfl(v1, 0);
        float m = fmaxf(v0, v1b);
        #pragma unroll
        for (int off = 32; off >= 1; off >>= 1) m = fmaxf(m, __shfl_xor(m, off));
        float e0 = expf(v0 - m);
        float e1 = expf(v1b - m);
        float s = e0;
        #pragma unroll
        for (int off = 32; off >= 1; off >>= 1) s += __shfl_xor(s, off);
        s += e1;
        float inv = 1.0f / s;
        Batt[xr * 104 + lane] = f2bfu(e0 * inv);
        if (lane == 0) Batt[xr * 104 + 64] = f2bfu(e1 * inv);
    }
    __syncthreads();

    // stage 1
    f32x4 acc1[4][5];
    #pragma unroll
    for (int i = 0; i < 4; ++i)
        #pragma unroll
        for (int j = 0; j < 5; ++j) acc1[i][j] = (f32x4){0.f, 0.f, 0.f, 0.f};
    #pragma unroll
    for (int ks = 0; ks < 3; ++ks) {
        bf16x8 af[4], bfr[5];
        #pragma unroll
        for (int mi = 0; mi < 4; ++mi)
            af[mi] = *(const bf16x8*)(Fcs + (size_t)((wave * 4 + mi) * 16 + lr) * 96 + ks * 32 + quad * 8);
        #pragma unroll
        for (int nt = 0; nt < 5; ++nt)
            bfr[nt] = *(const bf16x8*)(Batt + (nt * 16 + lr) * 104 + ks * 32 + quad * 8);
        #pragma unroll
        for (int mi = 0; mi < 4; ++mi)
            #pragma unroll
            for (int nt = 0; nt < 5; ++nt)
                acc1[mi][nt] = __builtin_amdgcn_mfma_f32_16x16x32_bf16(af[mi], bfr[nt], acc1[mi][nt], 0, 0, 0);
    }
    #pragma unroll
    for (int nt = 0; nt < 5; ++nt) {
        int x = nt * 16 + lr;
        if (x < 65) {
            #pragma unroll
            for (int mi = 0; mi < 4; ++mi) {
                int wbase = (wave * 4 + mi) * 16 + quad * 4;
                #pragma unroll
                for (int r = 0; r < 4; ++r) {
                    int which = wbase + r;
                    int d = which & 127;
                    int kc = (which >> 7) * 80 + x;
                    A3[d * 168 + kc] = f2bfu(acc1[mi][nt][r]);
                }
            }
        }
    }
    __syncthreads();

    // stage 2
    f32x4 acc2[2][4];
    #pragma unroll
    for (int i = 0; i < 2; ++i)
        #pragma unroll
        for (int j = 0; j < 4; ++j) acc2[i][j] = (f32x4){0.f, 0.f, 0.f, 0.f};
    const ushort* Gh = Gcat + (size_t)h * 128 * 160;
    #pragma unroll
    for (int ks = 0; ks < 5; ++ks) {
        bf16x8 a2[2], b2[4];
        #pragma unroll
        for (int mi = 0; mi < 2; ++mi)
            a2[mi] = *(const bf16x8*)(A3 + ((wave * 2 + mi) * 16 + lr) * 168 + ks * 32 + quad * 8);
        #pragma unroll
        for (int nt = 0; nt < 4; ++nt)
            b2[nt] = *(const bf16x8*)(Gh + (size_t)(chalf * 64 + nt * 16 + lr) * 160 + ks * 32 + quad * 8);
        #pragma unroll
        for (int mi = 0; mi < 2; ++mi)
            #pragma unroll
            for (int nt = 0; nt < 4; ++nt)
                acc2[mi][nt] = __builtin_amdgcn_mfma_f32_16x16x32_bf16(a2[mi], b2[nt], acc2[mi][nt], 0, 0, 0);
    }
    #pragma unroll
    for (int mi = 0; mi < 2; ++mi) {
        int dbase = (wave * 2 + mi) * 16 + quad * 4;
        #pragma unroll
        for (int nt = 0; nt < 4; ++nt) {
            int c = chalf * 64 + nt * 16 + lr;
            union { ushort4 u4; ushort u[4]; } pk;
            #pragma unroll
            for (int r = 0; r < 4; ++r) pk.u[r] = f2bfu(acc2[mi][nt][r]);
            *(ushort4*)(Pt + ((size_t)(b * 128 + c)) * 1024 + h * 128 + dbase) = pk.u4;
        }
    }
}

// ---------------------------------------------------------------------------
// R_b = Wv @ P_b folded: Rt_b[n][u] = sum_vc Wvb[u][vc] * Pt_b[n][vc].
// One block per batch; M=N=128, K=1024 in 8 steps.
// ---------------------------------------------------------------------------
__global__ __launch_bounds__(256) void k_R(const ushort* __restrict__ Wvb,
                                           const ushort* __restrict__ Pt,
                                           ushort* __restrict__ Rt) {
    __shared__ ushort As[128 * 128];
    __shared__ ushort Bs[128 * 128];
    int tid = threadIdx.x;
    int wave = tid >> 6, lane = tid & 63;
    int b = blockIdx.x;
    const ushort* pb = Pt + (size_t)b * 128 * 1024;

    f32x4 acc[4][4];
    #pragma unroll
    for (int i = 0; i < 4; ++i)
        #pragma unroll
        for (int j = 0; j < 4; ++j) acc[i][j] = (f32x4){0.f, 0.f, 0.f, 0.f};

    int lr = lane & 15, lk = lane >> 4;
    int wr = (wave >> 1) * 64, wc = (wave & 1) * 64;

    for (int k0 = 0; k0 < 1024; k0 += 128) {
        __syncthreads();
        #pragma unroll
        for (int it = 0; it < 8; ++it) {
            int q = wave * 512 + it * 64 + lane;
            int row = q >> 4, cp = q & 15;
            int gc = cp ^ (row & 15);
            int lbase = (wave * 512 + it * 64) * 8;
            g2l16(Wvb + (size_t)row * 1024 + k0 + gc * 8, As + lbase);
            g2l16(pb + (size_t)row * 1024 + k0 + gc * 8, Bs + lbase);
        }
        __syncthreads();
        #pragma unroll
        for (int kk = 0; kk < 4; ++kk) {
            bf16x8 af[4], bfr[4];
            int c = kk * 4 + lk;
            #pragma unroll
            for (int i = 0; i < 4; ++i) {
                int m = wr + i * 16 + lr;
                af[i] = *(const bf16x8*)(As + m * 128 + (c ^ (m & 15)) * 8);
                int n = wc + i * 16 + lr;
                bfr[i] = *(const bf16x8*)(Bs + n * 128 + (c ^ (n & 15)) * 8);
            }
            #pragma unroll
            for (int i = 0; i < 4; ++i)
                #pragma unroll
                for (int j = 0; j < 4; ++j)
                    acc[i][j] = __builtin_amdgcn_mfma_f32_16x16x32_bf16(af[i], bfr[j], acc[i][j], 0, 0, 0);
        }
    }
    #pragma unroll
    for (int i = 0; i < 4; ++i) {
        int ubase = wr + i * 16 + lk * 4;
        #pragma unroll
        for (int j = 0; j < 4; ++j) {
            int n = wc + j * 16 + lr;
            union { ushort4 u4; ushort u[4]; } pk;
            #pragma unroll
            for (int r = 0; r < 4; ++r) pk.u[r] = f2bfu(acc[i][j][r]);
            *(ushort4*)(Rt + (size_t)b * 16384 + n * 128 + ubase) = pk.u4;
        }
    }
}

// ---------------------------------------------------------------------------
// out = Xb @ Rt_b^T + bias. M=32768 (128/block), N=128, K=128 one shot.
// ---------------------------------------------------------------------------
__global__ __launch_bounds__(256) void k_out(const __hip_bfloat16* __restrict__ Xb,
                                             const ushort* __restrict__ Rt,
                                             const float* __restrict__ bout,
                                             float* __restrict__ out) {
    __shared__ ushort As[128 * 128];
    __shared__ ushort Bs[128 * 128];
    int tid = threadIdx.x;
    int wave = tid >> 6, lane = tid & 63;
    int m0 = blockIdx.x * 128;
    int b = blockIdx.x >> 4;
    const ushort* ga = (const ushort*)Xb + (size_t)m0 * 128;
    const ushort* gb = Rt + (size_t)b * 16384;
    #pragma unroll
    for (int it = 0; it < 8; ++it) {
        int q = wave * 512 + it * 64 + lane;
        int row = q >> 4, cp = q & 15;
        int gc = cp ^ (row & 15);
        int lbase = (wave * 512 + it * 64) * 8;
        g2l16(ga + (size_t)row * 128 + gc * 8, As + lbase);
        g2l16(gb + (size_t)row * 128 + gc * 8, Bs + lbase);
    }
    __syncthreads();

    f32x4 acc[4][4];
    #pragma unroll
    for (int i = 0; i < 4; ++i)
        #pragma unroll
        for (int j = 0; j < 4; ++j) acc[i][j] = (f32x4){0.f, 0.f, 0.f, 0.f};

    int lr = lane & 15, lk = lane >> 4;
    int wr = (wave >> 1) * 64, wc = (wave & 1) * 64;
    #pragma unroll
    for (int kk = 0; kk < 4; ++kk) {
        bf16x8 af[4], bfr[4];
        int c = kk * 4 + lk;
        #pragma unroll
        for (int i = 0; i < 4; ++i) {
            int m = wr + i * 16 + lr;
            af[i] = *(const bf16x8*)(As + m * 128 + (c ^ (m & 15)) * 8);
            int n = wc + i * 16 + lr;
            bfr[i] = *(const bf16x8*)(Bs + n * 128 + (c ^ (n & 15)) * 8);
        }
        #pragma unroll
        for (int i = 0; i < 4; ++i)
            #pragma unroll
            for (int j = 0; j < 4; ++j)
                acc[i][j] = __builtin_amdgcn_mfma_f32_16x16x32_bf16(af[i], bfr[j], acc[i][j], 0, 0, 0);
    }

    #pragma unroll
    for (int i = 0; i < 4; ++i) {
        int gr = m0 + wr + i * 16 + lk * 4;
        #pragma unroll
        for (int j = 0; j < 4; ++j) {
            int gcol = wc + j * 16 + lr;
            float bias = bout[gcol];
            #pragma unroll
            for (int r = 0; r < 4; ++r)
                out[(size_t)(gr + r) * 128 + gcol] = acc[i][j][r] + bias;
        }
    }
}

extern "C" void kernel_launch(void* const* d_in, const int* in_sizes, int n_in,
                              void* d_out, int out_size, void* d_ws, size_t ws_size,
                              hipStream_t stream) {
    const float* x    = (const float*)d_in[0];
    const float* wqkv = (const float*)d_in[1];
    const float* wout = (const float*)d_in[2];
    const float* bout = (const float*)d_in[3];
    float* out = (float*)d_out;

    char* ws = (char*)d_ws;
    size_t off = 0;
    auto alloc = [&](size_t bytes) -> void* {
        void* p = (void*)(ws + off);
        off += (bytes + 255) & ~(size_t)255;
        return p;
    };
    __hip_bfloat16* Wt = (__hip_bfloat16*)alloc((size_t)NPAD * 128 * 2);       // 0.56 MB
    ushort* Gcat = (ushort*)alloc((size_t)8 * 128 * 160 * 2);                  // 320 KB
    ushort* Fcs  = (ushort*)alloc((size_t)256 * 96 * 2);                       // 48 KB
    ushort* Wvb  = (ushort*)alloc((size_t)128 * 1024 * 2);                     // 256 KB
    ushort* XQKT = (ushort*)alloc((size_t)QKT_ROWS * MROWS * 2);               // 71.3 MB
    __hip_bfloat16* Xb = (__hip_bfloat16*)alloc((size_t)MROWS * 128 * 2);      // 8.4 MB
    float* attp = (float*)alloc((size_t)128 * NCH * 4225 * 4);                 // 34.6 MB
    ushort* Pt  = (ushort*)alloc((size_t)16 * 128 * 1024 * 2);                 // 4.2 MB
    ushort* Rt  = (ushort*)alloc((size_t)16 * 128 * 128 * 2);                  // 512 KB

    k_misc<<<dim3(4760), 256, 0, stream>>>(x, wqkv, wout, Xb, Wvb, Gcat, Fcs);
    k_prep_wqk<<<dim3(32, 2), 256, 0, stream>>>(wqkv, Wt);
    k_gemm1m<<<dim3(17, 256), 256, 0, stream>>>(Xb, Wt, XQKT);
    k_attm<<<dim3(128, NCH), 64, 0, stream>>>(XQKT, attp);
    k_TP<<<dim3(2, 128), 256, 0, stream>>>(attp, Fcs, Gcat, Pt);
    k_R<<<dim3(16), 256, 0, stream>>>(Wvb, Pt, Rt);
    k_out<<<dim3(256), 256, 0, stream>>>(Xb, Rt, bout, out);
}

// Round 6
// 228.957 us; speedup vs baseline: 1.2946x; 1.2946x over previous
//
#include <hip/hip_runtime.h>
#include <hip/hip_bf16.h>
#include <math.h>

// Problem constants
#define NB    16
#define NSEQ  2048
#define MROWS (NB*NSEQ)        // 32768
#define NPAD  2176             // gemm1 cols: q [0,1056) + k [1056,2112) + pad
// Within q/k: freq F = h*65+f (0..519, pad 528). gg=F>>4, t=F&15:
//   re at col region*1056 + gg*32 + t, im at +16  -> re/im same lane, 16 apart.
// XQKT: [row F' = region*528 + F][m], 1088 rows.
#define QKT_ROWS 1088
#define NCH   16               // attm e-chunks of 128

typedef __attribute__((ext_vector_type(8))) short bf16x8;
typedef __attribute__((ext_vector_type(4))) float f32x4;

__device__ __forceinline__ void g2l16(const void* g, void* l) {
    __builtin_amdgcn_global_load_lds(
        (const __attribute__((address_space(1))) void*)g,
        (__attribute__((address_space(3))) void*)l, 16, 0, 0);
}

__device__ __forceinline__ ushort f2bfu(float x) {
    __hip_bfloat16 t = __float2bfloat16(x);
    return *reinterpret_cast<ushort*>(&t);
}

// ---------------------------------------------------------------------------
// Fused small preps: [0,4096) x->Xb cast; [4096,4224) Wv bf16 cast;
// [4224,4744) Gcat (irfft basis @ w_out); [4744,4760) Fcs table.
// ---------------------------------------------------------------------------
__global__ __launch_bounds__(256) void k_misc(const float* __restrict__ x,
                                              const float* __restrict__ wqkv,
                                              const float* __restrict__ wout,
                                              __hip_bfloat16* __restrict__ Xb,
                                              ushort* __restrict__ Wvb,
                                              ushort* __restrict__ Gcat,
                                              ushort* __restrict__ Fcs) {
    __shared__ float tc[128], ts[128];
    int tid = threadIdx.x;
    int bid = blockIdx.x;
    if (bid < 4096) {
        int i = bid * 256 + tid;
        float4 v = ((const float4*)x)[i];
        __hip_bfloat16 o[4] = {__float2bfloat16(v.x), __float2bfloat16(v.y),
                               __float2bfloat16(v.z), __float2bfloat16(v.w)};
        *(ushort4*)((ushort*)Xb + (size_t)i * 4) = *(const ushort4*)o;
    } else if (bid < 4224) {
        int u = bid - 4096;                // 0..127
        float4 v = *(const float4*)(wqkv + (size_t)u * 3072 + 2048 + tid * 4);
        ushort o[4] = {f2bfu(v.x), f2bfu(v.y), f2bfu(v.z), f2bfu(v.w)};
        *(ushort4*)(Wvb + (size_t)u * 1024 + tid * 4) = *(const ushort4*)o;
    } else if (bid < 4744) {
        int hx = bid - 4224;               // 0..519
        if (tid < 128) {
            float a = (float)tid / 64.0f;
            tc[tid] = cospif(a);
            ts[tid] = sinpif(a);
        }
        __syncthreads();
        if (tid < 128) {
            int h = hx / 65, xx = hx - h * 65;
            float w = (xx == 0 || xx == 64) ? (1.0f / 128.0f) : (2.0f / 128.0f);
            float ar = 0.f, ai = 0.f;
            #pragma unroll 8
            for (int d = 0; d < 128; ++d) {
                float wv = wout[(size_t)(h * 128 + d) * 128 + tid];
                int m = (xx * d) & 127;
                ar = fmaf(wv, tc[m], ar);
                ai = fmaf(wv, ts[m], ai);
            }
            ushort* gp = Gcat + ((size_t)(h * 128 + tid)) * 160;
            gp[xx] = f2bfu(ar * w);
            gp[80 + xx] = f2bfu(-ai * w);
            if (xx == 0) {
                for (int k = 65; k < 80; ++k) gp[k] = 0;
                for (int k = 145; k < 160; ++k) gp[k] = 0;
            }
        }
    } else {
        // Fcs[r][y]: r<128 cos(2pi r y/128); r>=128 -sin(...); y>=65 -> 0
        int r = (bid - 4744) * 16 + (tid >> 4);
        int d = r & 127;
        int y0 = (tid & 15) * 6;
        #pragma unroll
        for (int k = 0; k < 6; ++k) {
            int y = y0 + k;
            float v = 0.f;
            if (y < 65) {
                float a = (float)((d * y) & 127) / 64.0f;
                v = (r < 128) ? cospif(a) : -sinpif(a);
            }
            Fcs[r * 96 + y] = f2bfu(v);
        }
    }
}

// ---------------------------------------------------------------------------
// q/k DFT fold into Wt. Grid (32, 2): (reg,h,c-half) x r-half.
// n = reg*1056 + ((F>>4)<<5) + (F&15) + ri*16, F=h*65+f.
// ---------------------------------------------------------------------------
__global__ __launch_bounds__(256) void k_prep_wqk(const float* __restrict__ wqkv,
                                                  __hip_bfloat16* __restrict__ Wt) {
    __shared__ float lw[64][129];
    __shared__ float tc[128], ts[128];
    int tid = threadIdx.x;
    int bid = blockIdx.x;
    int ry = blockIdx.y;
    int reg = bid >> 4;
    int h = (bid >> 1) & 7;
    int c0 = (bid & 1) * 64;
    if (tid < 128) {
        float a = (float)tid / 64.0f;
        tc[tid] = cospif(a);
        ts[tid] = sinpif(a);
    }
    #pragma unroll
    for (int it = 0; it < 8; ++it) {
        int idx = it * 256 + tid;
        int cl = idx >> 5;
        int d4 = (idx & 31) << 2;
        float4 v = *(const float4*)(wqkv + (size_t)(c0 + cl) * 3072 + reg * 1024 + h * 128 + d4);
        lw[cl][d4] = v.x; lw[cl][d4 + 1] = v.y; lw[cl][d4 + 2] = v.z; lw[cl][d4 + 3] = v.w;
    }
    __syncthreads();
    int cl = tid & 63;
    int rr = tid >> 6;
    int rend = ry ? 130 : 65;
    for (int r = ry * 65 + rr; r < rend; r += 4) {
        int f = r >> 1, ri = r & 1;
        float acc = 0.f;
        if (ri) {
            #pragma unroll 16
            for (int d = 0; d < 128; ++d) acc = fmaf(lw[cl][d], -ts[(f * d) & 127], acc);
        } else {
            #pragma unroll 16
            for (int d = 0; d < 128; ++d) acc = fmaf(lw[cl][d], tc[(f * d) & 127], acc);
        }
        int F = h * 65 + f;
        int n = reg * 1056 + ((F >> 4) << 5) + (F & 15) + ri * 16;
        Wt[(size_t)n * 128 + c0 + cl] = __float2bfloat16(acc * (1.0f / 65.0f));
    }
}

// ---------------------------------------------------------------------------
// GEMM1 (MFMA): Xb[32768,128] @ Wt^T (q/k only). 128x128 tile, K=128 one shot.
// Epilogue: (re,im) same lane, adjacent j-tiles -> magnitude -> XQKT packed.
// ---------------------------------------------------------------------------
__global__ __launch_bounds__(256) void k_gemm1m(const __hip_bfloat16* __restrict__ Xb,
                                                const __hip_bfloat16* __restrict__ Wt,
                                                ushort* __restrict__ XQKT) {
    __shared__ ushort As[128 * 128];
    __shared__ ushort Bs[128 * 128];
    int tid = threadIdx.x;
    int wave = tid >> 6, lane = tid & 63;
    int n0 = blockIdx.x * 128;
    int m0 = blockIdx.y * 128;
    const ushort* ga = (const ushort*)Xb + (size_t)m0 * 128;
    const ushort* gb = (const ushort*)Wt + (size_t)n0 * 128;
    #pragma unroll
    for (int it = 0; it < 8; ++it) {
        int q = wave * 512 + it * 64 + lane;
        int row = q >> 4, cp = q & 15;
        int gc = cp ^ (row & 15);
        int lbase = (wave * 512 + it * 64) * 8;
        g2l16(ga + (size_t)row * 128 + gc * 8, As + lbase);
        g2l16(gb + (size_t)row * 128 + gc * 8, Bs + lbase);
    }
    __syncthreads();

    f32x4 acc[4][4];
    #pragma unroll
    for (int i = 0; i < 4; ++i)
        #pragma unroll
        for (int j = 0; j < 4; ++j) acc[i][j] = (f32x4){0.f, 0.f, 0.f, 0.f};

    int lr = lane & 15, lk = lane >> 4;
    int wr = (wave >> 1) * 64, wc = (wave & 1) * 64;
    #pragma unroll
    for (int kk = 0; kk < 4; ++kk) {
        bf16x8 af[4], bfr[4];
        int c = kk * 4 + lk;
        #pragma unroll
        for (int i = 0; i < 4; ++i) {
            int m = wr + i * 16 + lr;
            af[i] = *(const bf16x8*)(As + m * 128 + (c ^ (m & 15)) * 8);
            int n = wc + i * 16 + lr;
            bfr[i] = *(const bf16x8*)(Bs + n * 128 + (c ^ (n & 15)) * 8);
        }
        #pragma unroll
        for (int i = 0; i < 4; ++i)
            #pragma unroll
            for (int j = 0; j < 4; ++j)
                acc[i][j] = __builtin_amdgcn_mfma_f32_16x16x32_bf16(af[i], bfr[j], acc[i][j], 0, 0, 0);
    }

    #pragma unroll
    for (int i = 0; i < 4; ++i) {
        int gr = m0 + wr + i * 16 + lk * 4;
        #pragma unroll
        for (int jp = 0; jp < 2; ++jp) {
            int cb = n0 + wc + jp * 32;
            if (cb < 2112) {
                int region = (cb >= 1056) ? 1 : 0;
                int local = cb - region * 1056;
                int row = region * 528 + ((local >> 5) << 4) + lr;
                f32x4 re = acc[i][2 * jp], im = acc[i][2 * jp + 1];
                union { ushort4 u4; ushort u[4]; } pk;
                #pragma unroll
                for (int r = 0; r < 4; ++r)
                    pk.u[r] = f2bfu(sqrtf(re[r] * re[r] + im[r] * im[r]));
                *(ushort4*)(XQKT + (size_t)row * MROWS + gr) = pk.u4;
            }
        }
    }
}

// ---------------------------------------------------------------------------
// att partials via MFMA. One wave per (bh, 128-e chunk). 5x5 tiles of 16x16,
// 4 K-substeps of 32 e. LDS pitch 5 chunks -> conflict-free.
// ---------------------------------------------------------------------------
__global__ __launch_bounds__(64) void k_attm(const ushort* __restrict__ XQKT,
                                             float* __restrict__ attp) {
    __shared__ ushort S[800 * 8];          // Q: chunks 0..399, K: 400..799
    int lane = threadIdx.x;
    int bh = blockIdx.x, ch = blockIdx.y;
    int b = bh >> 3, h = bh & 7;
    size_t e0 = (size_t)b * NSEQ + ch * 128;
    int qrow0 = h * 65, krow0 = 528 + h * 65;

    int srow[13], sco[13];
    #pragma unroll
    for (int r = 0; r < 13; ++r) {
        int s = r * 64 + lane;
        int mat = (s >= 400) ? 1 : 0;
        int ci = s - mat * 400;
        int f = ci / 5;
        int cp = ci - f * 5;
        srow[r] = (mat ? krow0 : qrow0) + f;
        sco[r] = (cp < 4) ? cp * 8 : 0;
    }

    f32x4 acc[5][5];
    #pragma unroll
    for (int i = 0; i < 5; ++i)
        #pragma unroll
        for (int j = 0; j < 5; ++j) acc[i][j] = (f32x4){0.f, 0.f, 0.f, 0.f};
    int lr = lane & 15, quad = lane >> 4;

    for (int sub = 0; sub < 4; ++sub) {
        __syncthreads();
        size_t ebase = e0 + sub * 32;
        #pragma unroll
        for (int r = 0; r < 12; ++r)
            g2l16(XQKT + (size_t)srow[r] * MROWS + ebase + sco[r], S + r * 64 * 8);
        if (lane < 32)
            g2l16(XQKT + (size_t)srow[12] * MROWS + ebase + sco[12], S + 12 * 64 * 8);
        __syncthreads();
        bf16x8 af[5], bfr[5];
        #pragma unroll
        for (int t5 = 0; t5 < 5; ++t5) {
            af[t5]  = *(const bf16x8*)(S + (t5 * 16 + lr) * 40 + quad * 8);
            bfr[t5] = *(const bf16x8*)(S + 3200 + (t5 * 16 + lr) * 40 + quad * 8);
        }
        #pragma unroll
        for (int tr = 0; tr < 5; ++tr)
            #pragma unroll
            for (int tc = 0; tc < 5; ++tc)
                acc[tr][tc] = __builtin_amdgcn_mfma_f32_16x16x32_bf16(af[tr], bfr[tc], acc[tr][tc], 0, 0, 0);
    }

    float* outp = attp + ((size_t)bh * NCH + ch) * 4225;
    #pragma unroll
    for (int tr = 0; tr < 5; ++tr) {
        #pragma unroll
        for (int tc = 0; tc < 5; ++tc) {
            int y = tc * 16 + lr;
            int x0 = tr * 16 + quad * 4;
            if (y < 65) {
                #pragma unroll
                for (int rr = 0; rr < 4; ++rr) {
                    int x = x0 + rr;
                    if (x < 65) outp[x * 65 + y] = acc[tr][tc][rr];
                }
            }
        }
    }
}

// ---------------------------------------------------------------------------
// Sum NCH partials + softmax over y. One wave per (x,bh) row -> 8320 waves.
// ---------------------------------------------------------------------------
__global__ void k_softmax(const float* __restrict__ attp, float* __restrict__ att) {
    int xx = blockIdx.x;                   // 0..64
    int bh = blockIdx.y;                   // 0..127
    int lane = threadIdx.x;                // 64
    const float* base = attp + (size_t)bh * NCH * 4225 + xx * 65;
    float v0 = 0.f, v1 = 0.f;
    #pragma unroll
    for (int c = 0; c < NCH; ++c) {
        v0 += base[(size_t)c * 4225 + lane];
        if (lane == 0) v1 += base[(size_t)c * 4225 + 64];
    }
    float v1b = __shfl(v1, 0);
    float m = fmaxf(v0, v1b);
    #pragma unroll
    for (int off = 32; off >= 1; off >>= 1) m = fmaxf(m, __shfl_xor(m, off));
    float e0 = expf(v0 - m);
    float e1 = expf(v1b - m);
    float s = e0;
    #pragma unroll
    for (int off = 32; off >= 1; off >>= 1) s += __shfl_xor(s, off);
    s += e1;
    float inv = 1.0f / s;
    att[(size_t)bh * 4225 + xx * 65 + lane] = e0 * inv;
    if (lane == 0) att[(size_t)bh * 4225 + xx * 65 + 64] = e1 * inv;
}

// ---------------------------------------------------------------------------
// Fused T+P per (chalf, bh) block (reads reduced att):
// Stage 1: [Fc;Fs][256,96] @ Batt^T -> A3 via LDS (C->A layout, pads zeroed)
// Stage 2: A3[128,160] @ Gcat^T -> Pt[b][c][h*128+d]
// Pitches 104/168 -> conflict-free fragment reads.
// ---------------------------------------------------------------------------
__global__ __launch_bounds__(256) void k_TP(const float* __restrict__ att,
                                            const ushort* __restrict__ Fcs,
                                            const ushort* __restrict__ Gcat,
                                            ushort* __restrict__ Pt) {
    __shared__ ushort Batt[80 * 104];
    __shared__ ushort A3[128 * 168];
    int tid = threadIdx.x;
    int wave = tid >> 6, lane = tid & 63;
    int lr = lane & 15, quad = lane >> 4;
    int chalf = blockIdx.x, bh = blockIdx.y;
    int b = bh >> 3, h = bh & 7;

    uint2 z2; z2.x = 0; z2.y = 0;
    uint2* A3v = (uint2*)A3;
    #pragma unroll 4
    for (int i = tid; i < 128 * 168 / 4; i += 256) A3v[i] = z2;
    uint2* Bv = (uint2*)Batt;
    #pragma unroll 4
    for (int i = tid; i < 80 * 104 / 4; i += 256) Bv[i] = z2;
    __syncthreads();
    const float* ab = att + (size_t)bh * 4225;
    for (int i = tid; i < 4225; i += 256) {
        int x = i / 65, y = i - x * 65;
        Batt[x * 104 + y] = f2bfu(ab[i]);
    }
    __syncthreads();

    // stage 1
    f32x4 acc1[4][5];
    #pragma unroll
    for (int i = 0; i < 4; ++i)
        #pragma unroll
        for (int j = 0; j < 5; ++j) acc1[i][j] = (f32x4){0.f, 0.f, 0.f, 0.f};
    #pragma unroll
    for (int ks = 0; ks < 3; ++ks) {
        bf16x8 af[4], bfr[5];
        #pragma unroll
        for (int mi = 0; mi < 4; ++mi)
            af[mi] = *(const bf16x8*)(Fcs + (size_t)((wave * 4 + mi) * 16 + lr) * 96 + ks * 32 + quad * 8);
        #pragma unroll
        for (int nt = 0; nt < 5; ++nt)
            bfr[nt] = *(const bf16x8*)(Batt + (nt * 16 + lr) * 104 + ks * 32 + quad * 8);
        #pragma unroll
        for (int mi = 0; mi < 4; ++mi)
            #pragma unroll
            for (int nt = 0; nt < 5; ++nt)
                acc1[mi][nt] = __builtin_amdgcn_mfma_f32_16x16x32_bf16(af[mi], bfr[nt], acc1[mi][nt], 0, 0, 0);
    }
    #pragma unroll
    for (int nt = 0; nt < 5; ++nt) {
        int x = nt * 16 + lr;
        if (x < 65) {
            #pragma unroll
            for (int mi = 0; mi < 4; ++mi) {
                int wbase = (wave * 4 + mi) * 16 + quad * 4;
                #pragma unroll
                for (int r = 0; r < 4; ++r) {
                    int which = wbase + r;
                    int d = which & 127;
                    int kc = (which >> 7) * 80 + x;
                    A3[d * 168 + kc] = f2bfu(acc1[mi][nt][r]);
                }
            }
        }
    }
    __syncthreads();

    // stage 2
    f32x4 acc2[2][4];
    #pragma unroll
    for (int i = 0; i < 2; ++i)
        #pragma unroll
        for (int j = 0; j < 4; ++j) acc2[i][j] = (f32x4){0.f, 0.f, 0.f, 0.f};
    const ushort* Gh = Gcat + (size_t)h * 128 * 160;
    #pragma unroll
    for (int ks = 0; ks < 5; ++ks) {
        bf16x8 a2[2], b2[4];
        #pragma unroll
        for (int mi = 0; mi < 2; ++mi)
            a2[mi] = *(const bf16x8*)(A3 + ((wave * 2 + mi) * 16 + lr) * 168 + ks * 32 + quad * 8);
        #pragma unroll
        for (int nt = 0; nt < 4; ++nt)
            b2[nt] = *(const bf16x8*)(Gh + (size_t)(chalf * 64 + nt * 16 + lr) * 160 + ks * 32 + quad * 8);
        #pragma unroll
        for (int mi = 0; mi < 2; ++mi)
            #pragma unroll
            for (int nt = 0; nt < 4; ++nt)
                acc2[mi][nt] = __builtin_amdgcn_mfma_f32_16x16x32_bf16(a2[mi], b2[nt], acc2[mi][nt], 0, 0, 0);
    }
    #pragma unroll
    for (int mi = 0; mi < 2; ++mi) {
        int dbase = (wave * 2 + mi) * 16 + quad * 4;
        #pragma unroll
        for (int nt = 0; nt < 4; ++nt) {
            int c = chalf * 64 + nt * 16 + lr;
            union { ushort4 u4; ushort u[4]; } pk;
            #pragma unroll
            for (int r = 0; r < 4; ++r) pk.u[r] = f2bfu(acc2[mi][nt][r]);
            *(ushort4*)(Pt + ((size_t)(b * 128 + c)) * 1024 + h * 128 + dbase) = pk.u4;
        }
    }
}

// ---------------------------------------------------------------------------
// R_b = Wv @ P_b folded: Rt_b[n][u] = sum_vc Wvb[u][vc] * Pt_b[n][vc].
// One block per batch; M=N=128, K=1024 in 8 steps.
// ---------------------------------------------------------------------------
__global__ __launch_bounds__(256) void k_R(const ushort* __restrict__ Wvb,
                                           const ushort* __restrict__ Pt,
                                           ushort* __restrict__ Rt) {
    __shared__ ushort As[128 * 128];
    __shared__ ushort Bs[128 * 128];
    int tid = threadIdx.x;
    int wave = tid >> 6, lane = tid & 63;
    int b = blockIdx.x;
    const ushort* pb = Pt + (size_t)b * 128 * 1024;

    f32x4 acc[4][4];
    #pragma unroll
    for (int i = 0; i < 4; ++i)
        #pragma unroll
        for (int j = 0; j < 4; ++j) acc[i][j] = (f32x4){0.f, 0.f, 0.f, 0.f};

    int lr = lane & 15, lk = lane >> 4;
    int wr = (wave >> 1) * 64, wc = (wave & 1) * 64;

    for (int k0 = 0; k0 < 1024; k0 += 128) {
        __syncthreads();
        #pragma unroll
        for (int it = 0; it < 8; ++it) {
            int q = wave * 512 + it * 64 + lane;
            int row = q >> 4, cp = q & 15;
            int gc = cp ^ (row & 15);
            int lbase = (wave * 512 + it * 64) * 8;
            g2l16(Wvb + (size_t)row * 1024 + k0 + gc * 8, As + lbase);
            g2l16(pb + (size_t)row * 1024 + k0 + gc * 8, Bs + lbase);
        }
        __syncthreads();
        #pragma unroll
        for (int kk = 0; kk < 4; ++kk) {
            bf16x8 af[4], bfr[4];
            int c = kk * 4 + lk;
            #pragma unroll
            for (int i = 0; i < 4; ++i) {
                int m = wr + i * 16 + lr;
                af[i] = *(const bf16x8*)(As + m * 128 + (c ^ (m & 15)) * 8);
                int n = wc + i * 16 + lr;
                bfr[i] = *(const bf16x8*)(Bs + n * 128 + (c ^ (n & 15)) * 8);
            }
            #pragma unroll
            for (int i = 0; i < 4; ++i)
                #pragma unroll
                for (int j = 0; j < 4; ++j)
                    acc[i][j] = __builtin_amdgcn_mfma_f32_16x16x32_bf16(af[i], bfr[j], acc[i][j], 0, 0, 0);
        }
    }
    #pragma unroll
    for (int i = 0; i < 4; ++i) {
        int ubase = wr + i * 16 + lk * 4;
        #pragma unroll
        for (int j = 0; j < 4; ++j) {
            int n = wc + j * 16 + lr;
            union { ushort4 u4; ushort u[4]; } pk;
            #pragma unroll
            for (int r = 0; r < 4; ++r) pk.u[r] = f2bfu(acc[i][j][r]);
            *(ushort4*)(Rt + (size_t)b * 16384 + n * 128 + ubase) = pk.u4;
        }
    }
}

// ---------------------------------------------------------------------------
// out = Xb @ Rt_b^T + bias. M=32768 (128/block), N=128, K=128 one shot.
// ---------------------------------------------------------------------------
__global__ __launch_bounds__(256) void k_out(const __hip_bfloat16* __restrict__ Xb,
                                             const ushort* __restrict__ Rt,
                                             const float* __restrict__ bout,
                                             float* __restrict__ out) {
    __shared__ ushort As[128 * 128];
    __shared__ ushort Bs[128 * 128];
    int tid = threadIdx.x;
    int wave = tid >> 6, lane = tid & 63;
    int m0 = blockIdx.x * 128;
    int b = blockIdx.x >> 4;
    const ushort* ga = (const ushort*)Xb + (size_t)m0 * 128;
    const ushort* gb = Rt + (size_t)b * 16384;
    #pragma unroll
    for (int it = 0; it < 8; ++it) {
        int q = wave * 512 + it * 64 + lane;
        int row = q >> 4, cp = q & 15;
        int gc = cp ^ (row & 15);
        int lbase = (wave * 512 + it * 64) * 8;
        g2l16(ga + (size_t)row * 128 + gc * 8, As + lbase);
        g2l16(gb + (size_t)row * 128 + gc * 8, Bs + lbase);
    }
    __syncthreads();

    f32x4 acc[4][4];
    #pragma unroll
    for (int i = 0; i < 4; ++i)
        #pragma unroll
        for (int j = 0; j < 4; ++j) acc[i][j] = (f32x4){0.f, 0.f, 0.f, 0.f};

    int lr = lane & 15, lk = lane >> 4;
    int wr = (wave >> 1) * 64, wc = (wave & 1) * 64;
    #pragma unroll
    for (int kk = 0; kk < 4; ++kk) {
        bf16x8 af[4], bfr[4];
        int c = kk * 4 + lk;
        #pragma unroll
        for (int i = 0; i < 4; ++i) {
            int m = wr + i * 16 + lr;
            af[i] = *(const bf16x8*)(As + m * 128 + (c ^ (m & 15)) * 8);
            int n = wc + i * 16 + lr;
            bfr[i] = *(const bf16x8*)(Bs + n * 128 + (c ^ (n & 15)) * 8);
        }
        #pragma unroll
        for (int i = 0; i < 4; ++i)
            #pragma unroll
            for (int j = 0; j < 4; ++j)
                acc[i][j] = __builtin_amdgcn_mfma_f32_16x16x32_bf16(af[i], bfr[j], acc[i][j], 0, 0, 0);
    }

    #pragma unroll
    for (int i = 0; i < 4; ++i) {
        int gr = m0 + wr + i * 16 + lk * 4;
        #pragma unroll
        for (int j = 0; j < 4; ++j) {
            int gcol = wc + j * 16 + lr;
            float bias = bout[gcol];
            #pragma unroll
            for (int r = 0; r < 4; ++r)
                out[(size_t)(gr + r) * 128 + gcol] = acc[i][j][r] + bias;
        }
    }
}

extern "C" void kernel_launch(void* const* d_in, const int* in_sizes, int n_in,
                              void* d_out, int out_size, void* d_ws, size_t ws_size,
                              hipStream_t stream) {
    const float* x    = (const float*)d_in[0];
    const float* wqkv = (const float*)d_in[1];
    const float* wout = (const float*)d_in[2];
    const float* bout = (const float*)d_in[3];
    float* out = (float*)d_out;

    char* ws = (char*)d_ws;
    size_t off = 0;
    auto alloc = [&](size_t bytes) -> void* {
        void* p = (void*)(ws + off);
        off += (bytes + 255) & ~(size_t)255;
        return p;
    };
    __hip_bfloat16* Wt = (__hip_bfloat16*)alloc((size_t)NPAD * 128 * 2);       // 0.56 MB
    ushort* Gcat = (ushort*)alloc((size_t)8 * 128 * 160 * 2);                  // 320 KB
    ushort* Fcs  = (ushort*)alloc((size_t)256 * 96 * 2);                       // 48 KB
    ushort* Wvb  = (ushort*)alloc((size_t)128 * 1024 * 2);                     // 256 KB
    ushort* XQKT = (ushort*)alloc((size_t)QKT_ROWS * MROWS * 2);               // 71.3 MB
    __hip_bfloat16* Xb = (__hip_bfloat16*)alloc((size_t)MROWS * 128 * 2);      // 8.4 MB
    float* attp = (float*)alloc((size_t)128 * NCH * 4225 * 4);                 // 34.6 MB
    float* att  = (float*)alloc((size_t)128 * 4225 * 4);                       // 2.2 MB
    ushort* Pt  = (ushort*)alloc((size_t)16 * 128 * 1024 * 2);                 // 4.2 MB
    ushort* Rt  = (ushort*)alloc((size_t)16 * 128 * 128 * 2);                  // 512 KB

    k_misc<<<dim3(4760), 256, 0, stream>>>(x, wqkv, wout, Xb, Wvb, Gcat, Fcs);
    k_prep_wqk<<<dim3(32, 2), 256, 0, stream>>>(wqkv, Wt);
    k_gemm1m<<<dim3(17, 256), 256, 0, stream>>>(Xb, Wt, XQKT);
    k_attm<<<dim3(128, NCH), 64, 0, stream>>>(XQKT, attp);
    k_softmax<<<dim3(65, 128), 64, 0, stream>>>(attp, att);
    k_TP<<<dim3(2, 128), 256, 0, stream>>>(att, Fcs, Gcat, Pt);
    k_R<<<dim3(16), 256, 0, stream>>>(Wvb, Pt, Rt);
    k_out<<<dim3(256), 256, 0, stream>>>(Xb, Rt, bout, out);
}